// Round 1
// baseline (3118.509 us; speedup 1.0000x reference)
//
#include <hip/hip_runtime.h>

#define NN 50000
#define NE 800000
#define DD 128

// ---------------- degree / norm precompute ----------------

__global__ void deg_init(float* __restrict__ deg) {
    int i = blockIdx.x * blockDim.x + threadIdx.x;
    if (i < NN) deg[i] = 1.0f;  // self-loop weight
}

__global__ void deg_accum(const int* __restrict__ col, const float* __restrict__ ew,
                          float* __restrict__ deg) {
    int e = blockIdx.x * blockDim.x + threadIdx.x;
    if (e < NE) atomicAdd(&deg[col[e]], ew[e]);
}

__global__ void dis_kernel(float* __restrict__ deg) {
    int i = blockIdx.x * blockDim.x + threadIdx.x;
    if (i < NN) {
        float d = deg[i];                 // >= 1.0 always (self-loop)
        deg[i] = rsqrtf(fmaxf(d, 1e-12f));
    }
}

__global__ void norm_kernel(const int* __restrict__ row, const int* __restrict__ col,
                            const float* __restrict__ ew, const float* __restrict__ dis,
                            float* __restrict__ norm) {
    int e = blockIdx.x * blockDim.x + threadIdx.x;
    if (e < NE) norm[e] = dis[row[e]] * ew[e] * dis[col[e]];
}

// ---------------- GEMM: out[n,128] = (relu?)in[n,128] @ W[128,128] ----------------
// One wave per row; lane computes cols (lane, lane+64). W staged in LDS.
// LDS bank pattern Ws[k*128+lane]: bank = lane%32 -> 2-way alias across 64 lanes (free).

template <bool RELU>
__global__ __launch_bounds__(256) void gemm128(const float* __restrict__ in,
                                               const float* __restrict__ W,
                                               float* __restrict__ out, int nrows) {
    __shared__ float Ws[DD * DD];
    const float4* W4 = (const float4*)W;
    float4* Ws4 = (float4*)Ws;
    for (int i = threadIdx.x; i < DD * DD / 4; i += 256) Ws4[i] = W4[i];
    __syncthreads();

    int wave = threadIdx.x >> 6;
    int lane = threadIdx.x & 63;
    int row = blockIdx.x * 4 + wave;
    if (row >= nrows) return;

    const float* xr = in + (size_t)row * DD;
    float xa = xr[lane];
    float xb = xr[lane + 64];
    if (RELU) { xa = fmaxf(xa, 0.0f); xb = fmaxf(xb, 0.0f); }

    float acc0 = 0.0f, acc1 = 0.0f;
#pragma unroll
    for (int k = 0; k < 64; k++) {
        float xk = __shfl(xa, k);
        acc0 = fmaf(xk, Ws[k * DD + lane], acc0);
        acc1 = fmaf(xk, Ws[k * DD + lane + 64], acc1);
    }
#pragma unroll
    for (int k = 0; k < 64; k++) {
        float xk = __shfl(xb, k);
        acc0 = fmaf(xk, Ws[(k + 64) * DD + lane], acc0);
        acc1 = fmaf(xk, Ws[(k + 64) * DD + lane + 64], acc1);
    }
    out[(size_t)row * DD + lane] = acc0;
    out[(size_t)row * DD + lane + 64] = acc1;
}

// ---------------- aggregation ----------------
// out[i,:] = b[:] + dis[i]^2 * h[i,:]   (bias + self-loop edge, norm = dis*1*dis)

__global__ void agg_init(const float* __restrict__ h, const float* __restrict__ dis,
                         const float* __restrict__ b, float* __restrict__ out) {
    int t = blockIdx.x * blockDim.x + threadIdx.x;  // NN*32 threads, float4 each
    int i = t >> 5, s = t & 31;
    if (i >= NN) return;
    float d = dis[i];
    float d2 = d * d;
    float4 v = ((const float4*)(h + (size_t)i * DD))[s];
    float4 bb = ((const float4*)b)[s];
    float4 o;
    o.x = bb.x + d2 * v.x;
    o.y = bb.y + d2 * v.y;
    o.z = bb.z + d2 * v.z;
    o.w = bb.w + d2 * v.w;
    ((float4*)(out + (size_t)i * DD))[s] = o;
}

// 32 lanes per edge, float4 gather of h[row], 4 scalar f32 atomics to out[col].
__global__ void agg_edges(const int* __restrict__ row, const int* __restrict__ col,
                          const float* __restrict__ norm, const float* __restrict__ h,
                          float* __restrict__ out) {
    int t = blockIdx.x * blockDim.x + threadIdx.x;
    int e = t >> 5, s = t & 31;
    if (e >= NE) return;
    int r = row[e], c = col[e];
    float nm = norm[e];
    float4 v = ((const float4*)(h + (size_t)r * DD))[s];
    float* o = out + (size_t)c * DD + s * 4;
    atomicAdd(o + 0, nm * v.x);
    atomicAdd(o + 1, nm * v.y);
    atomicAdd(o + 2, nm * v.z);
    atomicAdd(o + 3, nm * v.w);
}

// ---------------- launch ----------------

extern "C" void kernel_launch(void* const* d_in, const int* in_sizes, int n_in,
                              void* d_out, int out_size, void* d_ws, size_t ws_size,
                              hipStream_t stream) {
    const float* x  = (const float*)d_in[0];
    const int*   ei = (const int*)d_in[1];     // [2,E] int
    const float* ew = (const float*)d_in[2];
    const float* W1 = (const float*)d_in[3];
    const float* b1 = (const float*)d_in[4];
    const float* W2 = (const float*)d_in[5];
    const float* b2 = (const float*)d_in[6];
    float* out = (float*)d_out;

    float* ws   = (float*)d_ws;
    float* dis  = ws;                          // NN
    float* nrm  = ws + NN;                     // NE
    float* hbuf = nrm + NE;                    // NN*DD  (offset 850000 floats, 16B-aligned)
    float* obuf = hbuf + (size_t)NN * DD;      // NN*DD

    const int* rowi = ei;                      // edge_index[0]
    const int* coli = ei + NE;                 // edge_index[1]

    // norm precompute (shared by both layers)
    deg_init<<<(NN + 255) / 256, 256, 0, stream>>>(dis);
    deg_accum<<<(NE + 255) / 256, 256, 0, stream>>>(coli, ew, dis);
    dis_kernel<<<(NN + 255) / 256, 256, 0, stream>>>(dis);
    norm_kernel<<<(NE + 255) / 256, 256, 0, stream>>>(rowi, coli, ew, dis, nrm);

    // layer 1: h1 = x @ W1 ; out1 = A_norm h1 + b1  (relu deferred to layer-2 load)
    gemm128<false><<<(NN + 3) / 4, 256, 0, stream>>>(x, W1, hbuf, NN);
    agg_init<<<(NN * 32 + 255) / 256, 256, 0, stream>>>(hbuf, dis, b1, obuf);
    agg_edges<<<(NE * 32) / 256, 256, 0, stream>>>(rowi, coli, nrm, hbuf, obuf);

    // layer 2: h2 = relu(out1) @ W2 ; out = A_norm h2 + b2
    gemm128<true><<<(NN + 3) / 4, 256, 0, stream>>>(obuf, W2, hbuf, NN);
    agg_init<<<(NN * 32 + 255) / 256, 256, 0, stream>>>(hbuf, dis, b2, out);
    agg_edges<<<(NE * 32) / 256, 256, 0, stream>>>(rowi, coli, nrm, hbuf, out);
}

// Round 2
// 638.721 us; speedup vs baseline: 4.8824x; 4.8824x over previous
//
#include <hip/hip_runtime.h>

#define NN 50000
#define NE 800000
#define DD 128

#define SCAN_TILE 512
#define NBLK ((NN + SCAN_TILE - 1) / SCAN_TILE)   // 98

// ---------------- init: zero histogram, deg = 1 (self-loop) ----------------

__global__ void init_kernel(float* __restrict__ deg, int* __restrict__ counts) {
    int i = blockIdx.x * blockDim.x + threadIdx.x;
    if (i < NN) { deg[i] = 1.0f; counts[i] = 0; }
}

// fused: degree accumulation + in-degree histogram
__global__ void deg_hist(const int* __restrict__ col, const float* __restrict__ ew,
                         float* __restrict__ deg, int* __restrict__ counts) {
    int e = blockIdx.x * blockDim.x + threadIdx.x;
    if (e < NE) {
        int c = col[e];
        atomicAdd(&deg[c], ew[e]);
        atomicAdd(&counts[c], 1);
    }
}

__global__ void dis_kernel(float* __restrict__ deg) {
    int i = blockIdx.x * blockDim.x + threadIdx.x;
    if (i < NN) deg[i] = rsqrtf(fmaxf(deg[i], 1e-12f));
}

// ---------------- hierarchical exclusive scan of counts -> offsets/cursor ----------------

__global__ __launch_bounds__(256) void block_reduce(const int* __restrict__ counts,
                                                    int* __restrict__ bsum) {
    __shared__ int s[256];
    int b = blockIdx.x, t = threadIdx.x;
    int i = b * SCAN_TILE + t;
    int v = 0;
    if (i < NN) v += counts[i];
    if (i + 256 < NN && t + 256 < SCAN_TILE) v += counts[i + 256];
    s[t] = v;
    __syncthreads();
    for (int o = 128; o > 0; o >>= 1) {
        if (t < o) s[t] += s[t + o];
        __syncthreads();
    }
    if (t == 0) bsum[b] = s[0];
}

__global__ void scan_partials(int* __restrict__ bsum, int* __restrict__ offsets) {
    if (threadIdx.x == 0) {
        int running = 0;
        for (int b = 0; b < NBLK; b++) {
            int t = bsum[b];
            bsum[b] = running;
            running += t;
        }
        offsets[NN] = running;   // == NE
    }
}

__global__ __launch_bounds__(512) void scan_block(const int* __restrict__ counts,
                                                  const int* __restrict__ bsum,
                                                  int* __restrict__ offsets,
                                                  int* __restrict__ cursor) {
    __shared__ int tmp[SCAN_TILE];
    int b = blockIdx.x, t = threadIdx.x;
    int i = b * SCAN_TILE + t;
    int v = (i < NN) ? counts[i] : 0;
    tmp[t] = v;
    __syncthreads();
    for (int off = 1; off < SCAN_TILE; off <<= 1) {
        int x = (t >= off) ? tmp[t - off] : 0;
        __syncthreads();
        tmp[t] += x;
        __syncthreads();
    }
    int excl = tmp[t] - v + bsum[b];
    if (i < NN) { offsets[i] = excl; cursor[i] = excl; }
}

// scatter edges into CSR slots: packed (src, norm) 8B records
__global__ void scatter_edges(const int* __restrict__ row, const int* __restrict__ col,
                              const float* __restrict__ ew, const float* __restrict__ dis,
                              int* __restrict__ cursor, uint2* __restrict__ epk) {
    int e = blockIdx.x * blockDim.x + threadIdx.x;
    if (e >= NE) return;
    int r = row[e], c = col[e];
    float nm = dis[r] * ew[e] * dis[c];
    int pos = atomicAdd(&cursor[c], 1);
    uint2 p;
    p.x = (unsigned)r;
    p.y = __float_as_uint(nm);
    epk[pos] = p;
}

// ---------------- GEMM: out[n,128] = (relu?)in[n,128] @ W[128,128] ----------------

template <bool RELU>
__global__ __launch_bounds__(256) void gemm128(const float* __restrict__ in,
                                               const float* __restrict__ W,
                                               float* __restrict__ out, int nrows) {
    __shared__ float Ws[DD * DD];
    const float4* W4 = (const float4*)W;
    float4* Ws4 = (float4*)Ws;
    for (int i = threadIdx.x; i < DD * DD / 4; i += 256) Ws4[i] = W4[i];
    __syncthreads();

    int wave = threadIdx.x >> 6;
    int lane = threadIdx.x & 63;
    int row = blockIdx.x * 4 + wave;
    if (row >= nrows) return;

    const float* xr = in + (size_t)row * DD;
    float xa = xr[lane];
    float xb = xr[lane + 64];
    if (RELU) { xa = fmaxf(xa, 0.0f); xb = fmaxf(xb, 0.0f); }

    float acc0 = 0.0f, acc1 = 0.0f;
#pragma unroll
    for (int k = 0; k < 64; k++) {
        float xk = __shfl(xa, k);
        acc0 = fmaf(xk, Ws[k * DD + lane], acc0);
        acc1 = fmaf(xk, Ws[k * DD + lane + 64], acc1);
    }
#pragma unroll
    for (int k = 0; k < 64; k++) {
        float xk = __shfl(xb, k);
        acc0 = fmaf(xk, Ws[(k + 64) * DD + lane], acc0);
        acc1 = fmaf(xk, Ws[(k + 64) * DD + lane + 64], acc1);
    }
    out[(size_t)row * DD + lane] = acc0;
    out[(size_t)row * DD + lane + 64] = acc1;
}

// ---------------- CSR gather aggregation (no atomics) ----------------
// 32 lanes per node; lane s owns float4 segment s. Fuses bias + self-loop.

__global__ __launch_bounds__(256) void agg_csr(const int* __restrict__ offsets,
                                               const uint2* __restrict__ epk,
                                               const float* __restrict__ h,
                                               const float* __restrict__ dis,
                                               const float* __restrict__ b,
                                               float* __restrict__ out) {
    int t = blockIdx.x * blockDim.x + threadIdx.x;
    int i = t >> 5, s = t & 31;
    if (i >= NN) return;

    const float4* h4 = (const float4*)h;
    float d = dis[i];
    float d2 = d * d;
    float4 hv = h4[(size_t)i * 32 + s];
    float4 bb = ((const float4*)b)[s];
    float4 acc;
    acc.x = bb.x + d2 * hv.x;
    acc.y = bb.y + d2 * hv.y;
    acc.z = bb.z + d2 * hv.z;
    acc.w = bb.w + d2 * hv.w;

    int start = offsets[i], end = offsets[i + 1];
    for (int j = start; j < end; j++) {
        uint2 p = epk[j];                       // broadcast across the 32 lanes
        float nm = __uint_as_float(p.y);
        float4 v = h4[(size_t)p.x * 32 + s];    // coalesced 512B row gather
        acc.x = fmaf(nm, v.x, acc.x);
        acc.y = fmaf(nm, v.y, acc.y);
        acc.z = fmaf(nm, v.z, acc.z);
        acc.w = fmaf(nm, v.w, acc.w);
    }
    ((float4*)out)[(size_t)i * 32 + s] = acc;
}

// ---------------- launch ----------------

extern "C" void kernel_launch(void* const* d_in, const int* in_sizes, int n_in,
                              void* d_out, int out_size, void* d_ws, size_t ws_size,
                              hipStream_t stream) {
    const float* x  = (const float*)d_in[0];
    const int*   ei = (const int*)d_in[1];
    const float* ew = (const float*)d_in[2];
    const float* W1 = (const float*)d_in[3];
    const float* b1 = (const float*)d_in[4];
    const float* W2 = (const float*)d_in[5];
    const float* b2 = (const float*)d_in[6];
    float* out = (float*)d_out;

    // workspace layout (4B words)
    float* ws      = (float*)d_ws;
    float* dis     = ws;                            // [0, 50000)
    int*   counts  = (int*)(ws + NN);               // [50000, 100000)
    int*   offsets = counts + NN;                   // [100000, 150001)
    int*   cursor  = offsets + NN + 1;              // [150001, 200001)
    int*   bsum    = cursor + NN;                   // [200001, 200129)
    uint2* epk     = (uint2*)(ws + 200132);         // 16B-aligned, NE uint2 = 1.6M words
    float* hbuf    = ws + 200132 + 2 * NE;          // word 1800132, 16B-aligned, NN*DD
    // total ~8.2M words = 32.8 MB; d_out doubles as layer-1 output buffer

    const int* rowi = ei;
    const int* coli = ei + NE;

    // ---- CSR + norm build (shared by both layers) ----
    init_kernel<<<(NN + 255) / 256, 256, 0, stream>>>(dis, counts);
    deg_hist<<<(NE + 255) / 256, 256, 0, stream>>>(coli, ew, dis, counts);
    dis_kernel<<<(NN + 255) / 256, 256, 0, stream>>>(dis);
    block_reduce<<<NBLK, 256, 0, stream>>>(counts, bsum);
    scan_partials<<<1, 64, 0, stream>>>(bsum, offsets);
    scan_block<<<NBLK, 512, 0, stream>>>(counts, bsum, offsets, cursor);
    scatter_edges<<<(NE + 255) / 256, 256, 0, stream>>>(rowi, coli, ew, dis, cursor, epk);

    // ---- layer 1: h1 = x @ W1 ; out1 = A_norm h1 + b1 (into d_out) ----
    gemm128<false><<<(NN + 3) / 4, 256, 0, stream>>>(x, W1, hbuf, NN);
    agg_csr<<<(NN * 32) / 256, 256, 0, stream>>>(offsets, epk, hbuf, dis, b1, out);

    // ---- layer 2: h2 = relu(out1) @ W2 ; out = A_norm h2 + b2 ----
    gemm128<true><<<(NN + 3) / 4, 256, 0, stream>>>(out, W2, hbuf, NN);
    agg_csr<<<(NN * 32) / 256, 256, 0, stream>>>(offsets, epk, hbuf, dis, b2, out);
}

// Round 3
// 395.813 us; speedup vs baseline: 7.8788x; 1.6137x over previous
//
#include <hip/hip_runtime.h>

#define NN 50000
#define NE 800000
#define DD 128

#define SCAN_TILE 512
#define NBLK ((NN + SCAN_TILE - 1) / SCAN_TILE)   // 98

typedef __attribute__((ext_vector_type(8))) short short8;
typedef __attribute__((ext_vector_type(4))) float floatx4;

// ---------------- init: zero histogram, deg = 1 (self-loop) ----------------

__global__ void init_kernel(float* __restrict__ deg, int* __restrict__ counts) {
    int i = blockIdx.x * blockDim.x + threadIdx.x;
    if (i < NN) { deg[i] = 1.0f; counts[i] = 0; }
}

__global__ void deg_hist(const int* __restrict__ col, const float* __restrict__ ew,
                         float* __restrict__ deg, int* __restrict__ counts) {
    int e = blockIdx.x * blockDim.x + threadIdx.x;
    if (e < NE) {
        int c = col[e];
        atomicAdd(&deg[c], ew[e]);
        atomicAdd(&counts[c], 1);
    }
}

__global__ void dis_kernel(float* __restrict__ deg) {
    int i = blockIdx.x * blockDim.x + threadIdx.x;
    if (i < NN) deg[i] = rsqrtf(fmaxf(deg[i], 1e-12f));
}

// ---------------- hierarchical exclusive scan ----------------

__global__ __launch_bounds__(256) void block_reduce(const int* __restrict__ counts,
                                                    int* __restrict__ bsum) {
    __shared__ int s[256];
    int b = blockIdx.x, t = threadIdx.x;
    int i = b * SCAN_TILE + t;
    int v = 0;
    if (i < NN) v += counts[i];
    if (i + 256 < NN && t + 256 < SCAN_TILE) v += counts[i + 256];
    s[t] = v;
    __syncthreads();
    for (int o = 128; o > 0; o >>= 1) {
        if (t < o) s[t] += s[t + o];
        __syncthreads();
    }
    if (t == 0) bsum[b] = s[0];
}

// one-block parallel scan over the NBLK partials (was a serial 1-thread loop)
__global__ __launch_bounds__(128) void scan_partials(int* __restrict__ bsum,
                                                     int* __restrict__ offsets) {
    __shared__ int s[128];
    int t = threadIdx.x;
    int v = (t < NBLK) ? bsum[t] : 0;
    s[t] = v;
    __syncthreads();
    for (int off = 1; off < 128; off <<= 1) {
        int x = (t >= off) ? s[t - off] : 0;
        __syncthreads();
        s[t] += x;
        __syncthreads();
    }
    if (t < NBLK) bsum[t] = s[t] - v;        // exclusive
    if (t == 127) offsets[NN] = s[NBLK - 1]; // == NE
}

__global__ __launch_bounds__(512) void scan_block(const int* __restrict__ counts,
                                                  const int* __restrict__ bsum,
                                                  int* __restrict__ offsets,
                                                  int* __restrict__ cursor) {
    __shared__ int tmp[SCAN_TILE];
    int b = blockIdx.x, t = threadIdx.x;
    int i = b * SCAN_TILE + t;
    int v = (i < NN) ? counts[i] : 0;
    tmp[t] = v;
    __syncthreads();
    for (int off = 1; off < SCAN_TILE; off <<= 1) {
        int x = (t >= off) ? tmp[t - off] : 0;
        __syncthreads();
        tmp[t] += x;
        __syncthreads();
    }
    int excl = tmp[t] - v + bsum[b];
    if (i < NN) { offsets[i] = excl; cursor[i] = excl; }
}

__global__ void scatter_edges(const int* __restrict__ row, const int* __restrict__ col,
                              const float* __restrict__ ew, const float* __restrict__ dis,
                              int* __restrict__ cursor, uint2* __restrict__ epk) {
    int e = blockIdx.x * blockDim.x + threadIdx.x;
    if (e >= NE) return;
    int r = row[e], c = col[e];
    float nm = dis[r] * ew[e] * dis[c];
    int pos = atomicAdd(&cursor[c], 1);
    uint2 p;
    p.x = (unsigned)r;
    p.y = __float_as_uint(nm);
    epk[pos] = p;
}

// ---------------- bf16x3 split helpers ----------------

__device__ __forceinline__ void split_bf16(float x, unsigned short& hi, unsigned short& lo) {
    unsigned u = __float_as_uint(x);
    unsigned h = (u + 0x7FFFu + ((u >> 16) & 1u)) >> 16;   // RN-even to bf16
    hi = (unsigned short)h;
    float fh = __uint_as_float(h << 16);
    float r = x - fh;
    unsigned u2 = __float_as_uint(r);
    lo = (unsigned short)((u2 + 0x7FFFu + ((u2 >> 16) & 1u)) >> 16);
}

// W[k][n] f32 -> WT_hi[n][k], WT_lo[n][k] bf16 (transposed, split)
__global__ void prep_w(const float* __restrict__ W, unsigned short* __restrict__ whi,
                       unsigned short* __restrict__ wlo) {
    int t = blockIdx.x * blockDim.x + threadIdx.x;   // 16384
    int k = t >> 7, n = t & 127;
    unsigned short h, l;
    split_bf16(W[t], h, l);
    whi[n * DD + k] = h;
    wlo[n * DD + k] = l;
}

// ---------------- MFMA GEMM: h[m,128] = (relu?)in[m,128] @ W ----------------
// 256 thr = 4 waves: wave = (rowgroup rg = wid>>1) x (colgroup cg = wid&1).
// Block covers 128 rows (4 chunks of 32); wave: 16 rows x 64 cols per strip.
// B-fragments (W) cached in registers across all strips; no LDS.

template <bool RELU>
__global__ __launch_bounds__(256, 2) void gemm_mfma(const float* __restrict__ in,
                                                    const unsigned short* __restrict__ whi,
                                                    const unsigned short* __restrict__ wlo,
                                                    float* __restrict__ out) {
    int lane = threadIdx.x & 63;
    int wid = threadIdx.x >> 6;
    int cg = wid & 1;
    int rg = wid >> 1;
    int l16 = lane & 15;
    int quad = lane >> 4;
    int koff_base = quad * 8;

    // ---- load B fragments into registers: 4 n-tiles x 4 k-steps, hi+lo ----
    short8 bhi[4][4], blo[4][4];
#pragma unroll
    for (int t = 0; t < 4; t++) {
        int n = cg * 64 + t * 16 + l16;
#pragma unroll
        for (int ks = 0; ks < 4; ks++) {
            int koff = ks * 32 + koff_base;
            bhi[t][ks] = *(const short8*)(whi + n * DD + koff);
            blo[t][ks] = *(const short8*)(wlo + n * DD + koff);
        }
    }

#pragma unroll
    for (int chunk = 0; chunk < 4; chunk++) {
        int base = blockIdx.x * 128 + chunk * 32 + rg * 16;
        int m = base + l16;
        int mld = (m < NN) ? m : 0;
        const float* xr = in + (size_t)mld * DD;

        // ---- A fragments: 4 k-steps, 8 consecutive f32 each, split hi/lo ----
        short8 ahi[4], alo[4];
#pragma unroll
        for (int ks = 0; ks < 4; ks++) {
            int koff = ks * 32 + koff_base;
            float4 a0 = *(const float4*)(xr + koff);
            float4 a1 = *(const float4*)(xr + koff + 4);
            float v[8] = {a0.x, a0.y, a0.z, a0.w, a1.x, a1.y, a1.z, a1.w};
#pragma unroll
            for (int j = 0; j < 8; j++) {
                float xv = RELU ? fmaxf(v[j], 0.0f) : v[j];
                unsigned short h, l;
                split_bf16(xv, h, l);
                ahi[ks][j] = (short)h;
                alo[ks][j] = (short)l;
            }
        }

        floatx4 acc[4];
#pragma unroll
        for (int t = 0; t < 4; t++) acc[t] = (floatx4)(0.0f);

#pragma unroll
        for (int ks = 0; ks < 4; ks++) {
#pragma unroll
            for (int t = 0; t < 4; t++) {
                acc[t] = __builtin_amdgcn_mfma_f32_16x16x32_bf16(ahi[ks], bhi[t][ks], acc[t], 0, 0, 0);
                acc[t] = __builtin_amdgcn_mfma_f32_16x16x32_bf16(alo[ks], bhi[t][ks], acc[t], 0, 0, 0);
                acc[t] = __builtin_amdgcn_mfma_f32_16x16x32_bf16(ahi[ks], blo[t][ks], acc[t], 0, 0, 0);
            }
        }

        // ---- store: D col = lane&15, row = quad*4 + reg ----
#pragma unroll
        for (int r = 0; r < 4; r++) {
            int rowm = base + quad * 4 + r;
            if (rowm < NN) {
                float* o = out + (size_t)rowm * DD + cg * 64 + l16;
#pragma unroll
                for (int t = 0; t < 4; t++) o[t * 16] = acc[t][r];
            }
        }
    }
}

// ---------------- CSR gather aggregation (no atomics), 4x unrolled ----------------

__global__ __launch_bounds__(256) void agg_csr(const int* __restrict__ offsets,
                                               const uint2* __restrict__ epk,
                                               const float* __restrict__ h,
                                               const float* __restrict__ dis,
                                               const float* __restrict__ b,
                                               float* __restrict__ out) {
    int t = blockIdx.x * blockDim.x + threadIdx.x;
    int i = t >> 5, s = t & 31;
    if (i >= NN) return;

    const float4* h4 = (const float4*)h;
    float d = dis[i];
    float d2 = d * d;
    float4 hv = h4[(size_t)i * 32 + s];
    float4 bb = ((const float4*)b)[s];
    float ax = bb.x + d2 * hv.x;
    float ay = bb.y + d2 * hv.y;
    float az = bb.z + d2 * hv.z;
    float aw = bb.w + d2 * hv.w;

    int start = offsets[i], end = offsets[i + 1];
    int j = start;
    for (; j + 4 <= end; j += 4) {
        uint2 p0 = epk[j], p1 = epk[j + 1], p2 = epk[j + 2], p3 = epk[j + 3];
        float4 v0 = h4[(size_t)p0.x * 32 + s];
        float4 v1 = h4[(size_t)p1.x * 32 + s];
        float4 v2 = h4[(size_t)p2.x * 32 + s];
        float4 v3 = h4[(size_t)p3.x * 32 + s];
        float n0 = __uint_as_float(p0.y), n1 = __uint_as_float(p1.y);
        float n2 = __uint_as_float(p2.y), n3 = __uint_as_float(p3.y);
        ax = fmaf(n0, v0.x, ax); ay = fmaf(n0, v0.y, ay);
        az = fmaf(n0, v0.z, az); aw = fmaf(n0, v0.w, aw);
        ax = fmaf(n1, v1.x, ax); ay = fmaf(n1, v1.y, ay);
        az = fmaf(n1, v1.z, az); aw = fmaf(n1, v1.w, aw);
        ax = fmaf(n2, v2.x, ax); ay = fmaf(n2, v2.y, ay);
        az = fmaf(n2, v2.z, az); aw = fmaf(n2, v2.w, aw);
        ax = fmaf(n3, v3.x, ax); ay = fmaf(n3, v3.y, ay);
        az = fmaf(n3, v3.z, az); aw = fmaf(n3, v3.w, aw);
    }
    for (; j < end; j++) {
        uint2 p = epk[j];
        float nm = __uint_as_float(p.y);
        float4 v = h4[(size_t)p.x * 32 + s];
        ax = fmaf(nm, v.x, ax); ay = fmaf(nm, v.y, ay);
        az = fmaf(nm, v.z, az); aw = fmaf(nm, v.w, aw);
    }
    float4 o; o.x = ax; o.y = ay; o.z = az; o.w = aw;
    ((float4*)out)[(size_t)i * 32 + s] = o;
}

// ---------------- launch ----------------

extern "C" void kernel_launch(void* const* d_in, const int* in_sizes, int n_in,
                              void* d_out, int out_size, void* d_ws, size_t ws_size,
                              hipStream_t stream) {
    const float* x  = (const float*)d_in[0];
    const int*   ei = (const int*)d_in[1];
    const float* ew = (const float*)d_in[2];
    const float* W1 = (const float*)d_in[3];
    const float* b1 = (const float*)d_in[4];
    const float* W2 = (const float*)d_in[5];
    const float* b2 = (const float*)d_in[6];
    float* out = (float*)d_out;

    // workspace layout (4B words)
    float* ws      = (float*)d_ws;
    float* dis     = ws;                            // [0, 50000)
    int*   counts  = (int*)(ws + NN);               // [50000, 100000)
    int*   offsets = counts + NN;                   // [100000, 150001)
    int*   cursor  = offsets + NN + 1;              // [150001, 200001)
    int*   bsum    = cursor + NN;                   // [200001, 200129)
    uint2* epk     = (uint2*)(ws + 200132);         // 16B-aligned, NE uint2
    float* hbuf    = ws + 200132 + 2 * NE;          // word 1800132, NN*DD
    unsigned short* wt1hi = (unsigned short*)(ws + 8200132);            // 16384 us = 8192 w
    unsigned short* wt1lo = (unsigned short*)(ws + 8208324);
    unsigned short* wt2hi = (unsigned short*)(ws + 8216516);
    unsigned short* wt2lo = (unsigned short*)(ws + 8224708);
    // total ~8.24M words = 33 MB

    const int* rowi = ei;
    const int* coli = ei + NE;

    // ---- CSR + norm + W-split build (shared / one-time) ----
    init_kernel<<<(NN + 255) / 256, 256, 0, stream>>>(dis, counts);
    deg_hist<<<(NE + 255) / 256, 256, 0, stream>>>(coli, ew, dis, counts);
    dis_kernel<<<(NN + 255) / 256, 256, 0, stream>>>(dis);
    block_reduce<<<NBLK, 256, 0, stream>>>(counts, bsum);
    scan_partials<<<1, 128, 0, stream>>>(bsum, offsets);
    scan_block<<<NBLK, 512, 0, stream>>>(counts, bsum, offsets, cursor);
    scatter_edges<<<(NE + 255) / 256, 256, 0, stream>>>(rowi, coli, ew, dis, cursor, epk);
    prep_w<<<64, 256, 0, stream>>>(W1, wt1hi, wt1lo);
    prep_w<<<64, 256, 0, stream>>>(W2, wt2hi, wt2lo);

    const int gemm_grid = (NN + 127) / 128;  // 391

    // ---- layer 1 ----
    gemm_mfma<false><<<gemm_grid, 256, 0, stream>>>(x, wt1hi, wt1lo, hbuf);
    agg_csr<<<(NN * 32) / 256, 256, 0, stream>>>(offsets, epk, hbuf, dis, b1, out);

    // ---- layer 2 ----
    gemm_mfma<true><<<gemm_grid, 256, 0, stream>>>(out, wt2hi, wt2lo, hbuf);
    agg_csr<<<(NN * 32) / 256, 256, 0, stream>>>(offsets, epk, hbuf, dis, b2, out);
}

// Round 4
// 337.280 us; speedup vs baseline: 9.2461x; 1.1735x over previous
//
#include <hip/hip_runtime.h>

#define NN 50000
#define NE 800000
#define DD 128

#define SCAN_TILE 512
#define NBLK ((NN + SCAN_TILE - 1) / SCAN_TILE)   // 98

typedef __attribute__((ext_vector_type(8))) short short8;
typedef __attribute__((ext_vector_type(4))) float floatx4;

// ---------------- init ----------------

__global__ void init_kernel(int* __restrict__ counts) {
    int i = blockIdx.x * blockDim.x + threadIdx.x;
    if (i < NN) counts[i] = 0;
}

// single atomic per edge: histogram + within-node rank
__global__ void hist_rank(const int* __restrict__ col, int* __restrict__ counts,
                          int* __restrict__ rank) {
    int e = blockIdx.x * blockDim.x + threadIdx.x;
    if (e < NE) rank[e] = atomicAdd(&counts[col[e]], 1);
}

// ---------------- hierarchical exclusive scan ----------------

__global__ __launch_bounds__(256) void block_reduce(const int* __restrict__ counts,
                                                    int* __restrict__ bsum) {
    __shared__ int s[256];
    int b = blockIdx.x, t = threadIdx.x;
    int i = b * SCAN_TILE + t;
    int v = 0;
    if (i < NN) v += counts[i];
    if (i + 256 < NN && t + 256 < SCAN_TILE) v += counts[i + 256];
    s[t] = v;
    __syncthreads();
    for (int o = 128; o > 0; o >>= 1) {
        if (t < o) s[t] += s[t + o];
        __syncthreads();
    }
    if (t == 0) bsum[b] = s[0];
}

__global__ __launch_bounds__(128) void scan_partials(int* __restrict__ bsum,
                                                     int* __restrict__ offsets) {
    __shared__ int s[128];
    int t = threadIdx.x;
    int v = (t < NBLK) ? bsum[t] : 0;
    s[t] = v;
    __syncthreads();
    for (int off = 1; off < 128; off <<= 1) {
        int x = (t >= off) ? s[t - off] : 0;
        __syncthreads();
        s[t] += x;
        __syncthreads();
    }
    if (t < NBLK) bsum[t] = s[t] - v;        // exclusive
    if (t == 127) offsets[NN] = s[NBLK - 1]; // == NE
}

__global__ __launch_bounds__(512) void scan_block(const int* __restrict__ counts,
                                                  const int* __restrict__ bsum,
                                                  int* __restrict__ offsets) {
    __shared__ int tmp[SCAN_TILE];
    int b = blockIdx.x, t = threadIdx.x;
    int i = b * SCAN_TILE + t;
    int v = (i < NN) ? counts[i] : 0;
    tmp[t] = v;
    __syncthreads();
    for (int off = 1; off < SCAN_TILE; off <<= 1) {
        int x = (t >= off) ? tmp[t - off] : 0;
        __syncthreads();
        tmp[t] += x;
        __syncthreads();
    }
    if (i < NN) offsets[i] = tmp[t] - v + bsum[b];
}

// place edges into CSR slots (no atomics): epk = (row, raw ew)
__global__ void place_edges(const int* __restrict__ row, const int* __restrict__ col,
                            const float* __restrict__ ew, const int* __restrict__ offsets,
                            const int* __restrict__ rank, uint2* __restrict__ epk) {
    int e = blockIdx.x * blockDim.x + threadIdx.x;
    if (e >= NE) return;
    int c = col[e];
    uint2 p;
    p.x = (unsigned)row[e];
    p.y = __float_as_uint(ew[e]);
    epk[offsets[c] + rank[e]] = p;
}

// deg/dis from CSR: contiguous segmented sum, 4 lanes per node
__global__ void deg_dis(const int* __restrict__ offsets, const uint2* __restrict__ epk,
                        float* __restrict__ dis) {
    int t = blockIdx.x * blockDim.x + threadIdx.x;
    int i = t >> 2, l = t & 3;
    if (i >= NN) return;
    float s = 0.0f;
    int start = offsets[i], end = offsets[i + 1];
    for (int j = start + l; j < end; j += 4) s += __uint_as_float(epk[j].y);
    s += __shfl_xor(s, 1);
    s += __shfl_xor(s, 2);
    if (l == 0) dis[i] = rsqrtf(fmaxf(1.0f + s, 1e-12f));  // +1 self-loop
}

// epk.y: ew -> ew * dis[row]  (contiguous pass, once for both layers)
__global__ void rescale(uint2* __restrict__ epk, const float* __restrict__ dis) {
    int e = blockIdx.x * blockDim.x + threadIdx.x;
    if (e < NE) {
        uint2 p = epk[e];
        epk[e].y = __float_as_uint(__uint_as_float(p.y) * dis[p.x]);
    }
}

// ---------------- bf16x3 split helpers ----------------

__device__ __forceinline__ void split_bf16(float x, unsigned short& hi, unsigned short& lo) {
    unsigned u = __float_as_uint(x);
    unsigned h = (u + 0x7FFFu + ((u >> 16) & 1u)) >> 16;   // RN-even to bf16
    hi = (unsigned short)h;
    float fh = __uint_as_float(h << 16);
    float r = x - fh;
    unsigned u2 = __float_as_uint(r);
    lo = (unsigned short)((u2 + 0x7FFFu + ((u2 >> 16) & 1u)) >> 16);
}

__global__ void prep_w(const float* __restrict__ W, unsigned short* __restrict__ whi,
                       unsigned short* __restrict__ wlo) {
    int t = blockIdx.x * blockDim.x + threadIdx.x;   // 16384
    int k = t >> 7, n = t & 127;
    unsigned short h, l;
    split_bf16(W[t], h, l);
    whi[n * DD + k] = h;
    wlo[n * DD + k] = l;
}

// ---------------- MFMA GEMM: h[m,128] = (relu?)in[m,128] @ W ----------------

template <bool RELU>
__global__ __launch_bounds__(256, 2) void gemm_mfma(const float* __restrict__ in,
                                                    const unsigned short* __restrict__ whi,
                                                    const unsigned short* __restrict__ wlo,
                                                    float* __restrict__ out) {
    int lane = threadIdx.x & 63;
    int wid = threadIdx.x >> 6;
    int cg = wid & 1;
    int rg = wid >> 1;
    int l16 = lane & 15;
    int quad = lane >> 4;
    int koff_base = quad * 8;

    short8 bhi[4][4], blo[4][4];
#pragma unroll
    for (int t = 0; t < 4; t++) {
        int n = cg * 64 + t * 16 + l16;
#pragma unroll
        for (int ks = 0; ks < 4; ks++) {
            int koff = ks * 32 + koff_base;
            bhi[t][ks] = *(const short8*)(whi + n * DD + koff);
            blo[t][ks] = *(const short8*)(wlo + n * DD + koff);
        }
    }

#pragma unroll
    for (int chunk = 0; chunk < 4; chunk++) {
        int base = blockIdx.x * 128 + chunk * 32 + rg * 16;
        int m = base + l16;
        int mld = (m < NN) ? m : 0;
        const float* xr = in + (size_t)mld * DD;

        short8 ahi[4], alo[4];
#pragma unroll
        for (int ks = 0; ks < 4; ks++) {
            int koff = ks * 32 + koff_base;
            float4 a0 = *(const float4*)(xr + koff);
            float4 a1 = *(const float4*)(xr + koff + 4);
            float v[8] = {a0.x, a0.y, a0.z, a0.w, a1.x, a1.y, a1.z, a1.w};
#pragma unroll
            for (int j = 0; j < 8; j++) {
                float xv = RELU ? fmaxf(v[j], 0.0f) : v[j];
                unsigned short h, l;
                split_bf16(xv, h, l);
                ahi[ks][j] = (short)h;
                alo[ks][j] = (short)l;
            }
        }

        floatx4 acc[4];
#pragma unroll
        for (int t = 0; t < 4; t++) acc[t] = (floatx4)(0.0f);

#pragma unroll
        for (int ks = 0; ks < 4; ks++) {
#pragma unroll
            for (int t = 0; t < 4; t++) {
                acc[t] = __builtin_amdgcn_mfma_f32_16x16x32_bf16(ahi[ks], bhi[t][ks], acc[t], 0, 0, 0);
                acc[t] = __builtin_amdgcn_mfma_f32_16x16x32_bf16(alo[ks], bhi[t][ks], acc[t], 0, 0, 0);
                acc[t] = __builtin_amdgcn_mfma_f32_16x16x32_bf16(ahi[ks], blo[t][ks], acc[t], 0, 0, 0);
            }
        }

#pragma unroll
        for (int r = 0; r < 4; r++) {
            int rowm = base + quad * 4 + r;
            if (rowm < NN) {
                float* o = out + (size_t)rowm * DD + cg * 64 + l16;
#pragma unroll
                for (int t = 0; t < 4; t++) o[t * 16] = acc[t][r];
            }
        }
    }
}

// ---------------- CSR gather aggregation ----------------
// One 64-lane wave per node; half-waves process edges j (half 0) / j+1 (half 1),
// 4x unrolled -> 8 gathers in flight. out = b + dis[i]*edge_sum + dis[i]^2*h[i].

__global__ __launch_bounds__(256) void agg_csr(const int* __restrict__ offsets,
                                               const uint2* __restrict__ epk,
                                               const float* __restrict__ h,
                                               const float* __restrict__ dis,
                                               const float* __restrict__ bias,
                                               float* __restrict__ out) {
    int i = (blockIdx.x * blockDim.x + threadIdx.x) >> 6;   // node
    int lane = threadIdx.x & 63;
    int s = lane & 31;
    int half = lane >> 5;
    if (i >= NN) return;

    const float4* h4 = (const float4*)h;
    float ax = 0.0f, ay = 0.0f, az = 0.0f, aw = 0.0f;

    int start = offsets[i], end = offsets[i + 1];
    int j = start + half;
    for (; j + 6 < end; j += 8) {
        uint2 p0 = epk[j], p1 = epk[j + 2], p2 = epk[j + 4], p3 = epk[j + 6];
        float4 v0 = h4[(size_t)p0.x * 32 + s];
        float4 v1 = h4[(size_t)p1.x * 32 + s];
        float4 v2 = h4[(size_t)p2.x * 32 + s];
        float4 v3 = h4[(size_t)p3.x * 32 + s];
        float n0 = __uint_as_float(p0.y), n1 = __uint_as_float(p1.y);
        float n2 = __uint_as_float(p2.y), n3 = __uint_as_float(p3.y);
        ax = fmaf(n0, v0.x, ax); ay = fmaf(n0, v0.y, ay);
        az = fmaf(n0, v0.z, az); aw = fmaf(n0, v0.w, aw);
        ax = fmaf(n1, v1.x, ax); ay = fmaf(n1, v1.y, ay);
        az = fmaf(n1, v1.z, az); aw = fmaf(n1, v1.w, aw);
        ax = fmaf(n2, v2.x, ax); ay = fmaf(n2, v2.y, ay);
        az = fmaf(n2, v2.z, az); aw = fmaf(n2, v2.w, aw);
        ax = fmaf(n3, v3.x, ax); ay = fmaf(n3, v3.y, ay);
        az = fmaf(n3, v3.z, az); aw = fmaf(n3, v3.w, aw);
    }
    for (; j < end; j += 2) {
        uint2 p = epk[j];
        float nm = __uint_as_float(p.y);
        float4 v = h4[(size_t)p.x * 32 + s];
        ax = fmaf(nm, v.x, ax); ay = fmaf(nm, v.y, ay);
        az = fmaf(nm, v.z, az); aw = fmaf(nm, v.w, aw);
    }

    // combine the two half-wave partial sums
    ax += __shfl_xor(ax, 32);
    ay += __shfl_xor(ay, 32);
    az += __shfl_xor(az, 32);
    aw += __shfl_xor(aw, 32);

    if (half == 0) {
        float d = dis[i];
        float d2 = d * d;
        float4 hv = h4[(size_t)i * 32 + s];
        float4 bb = ((const float4*)bias)[s];
        float4 o;
        o.x = bb.x + d * ax + d2 * hv.x;
        o.y = bb.y + d * ay + d2 * hv.y;
        o.z = bb.z + d * az + d2 * hv.z;
        o.w = bb.w + d * aw + d2 * hv.w;
        ((float4*)out)[(size_t)i * 32 + s] = o;
    }
}

// ---------------- launch ----------------

extern "C" void kernel_launch(void* const* d_in, const int* in_sizes, int n_in,
                              void* d_out, int out_size, void* d_ws, size_t ws_size,
                              hipStream_t stream) {
    const float* x  = (const float*)d_in[0];
    const int*   ei = (const int*)d_in[1];
    const float* ew = (const float*)d_in[2];
    const float* W1 = (const float*)d_in[3];
    const float* b1 = (const float*)d_in[4];
    const float* W2 = (const float*)d_in[5];
    const float* b2 = (const float*)d_in[6];
    float* out = (float*)d_out;

    // workspace layout (4B words)
    float* ws      = (float*)d_ws;
    float* dis     = ws;                              // [0, 50000)
    int*   counts  = (int*)(ws + NN);                 // [50000, 100000)
    int*   offsets = counts + NN;                     // [100000, 150001)
    int*   bsum    = offsets + NN + 1;                // [150001, 150099)
    uint2* epk     = (uint2*)(ws + 150100);           // byte 600400, 8B-aligned; NE uint2
    float* hbuf    = ws + 150100 + 2 * NE;            // word 1750100, byte 7000400, 16B-aligned
    int*   rank    = (int*)hbuf;                      // aliases hbuf: consumed before gemm writes
    unsigned short* wt1hi = (unsigned short*)(ws + 8150100);  // 8192 words each
    unsigned short* wt1lo = (unsigned short*)(ws + 8158292);
    unsigned short* wt2hi = (unsigned short*)(ws + 8166484);
    unsigned short* wt2lo = (unsigned short*)(ws + 8174676);
    // total ~8.18M words ~= 32.7 MB

    const int* rowi = ei;
    const int* coli = ei + NE;

    // ---- CSR build: 1 atomic per edge total ----
    init_kernel<<<(NN + 255) / 256, 256, 0, stream>>>(counts);
    hist_rank<<<(NE + 255) / 256, 256, 0, stream>>>(coli, counts, rank);
    block_reduce<<<NBLK, 256, 0, stream>>>(counts, bsum);
    scan_partials<<<1, 128, 0, stream>>>(bsum, offsets);
    scan_block<<<NBLK, 512, 0, stream>>>(counts, bsum, offsets);
    place_edges<<<(NE + 255) / 256, 256, 0, stream>>>(rowi, coli, ew, offsets, rank, epk);
    deg_dis<<<(NN * 4 + 255) / 256, 256, 0, stream>>>(offsets, epk, dis);
    rescale<<<(NE + 255) / 256, 256, 0, stream>>>(epk, dis);
    prep_w<<<64, 256, 0, stream>>>(W1, wt1hi, wt1lo);
    prep_w<<<64, 256, 0, stream>>>(W2, wt2hi, wt2lo);

    const int gemm_grid = (NN + 127) / 128;  // 391

    // ---- layer 1: h1 = x @ W1 ; out1 = A_norm h1 + b1 (into d_out) ----
    gemm_mfma<false><<<gemm_grid, 256, 0, stream>>>(x, wt1hi, wt1lo, hbuf);
    agg_csr<<<(NN * 64) / 256 + 1, 256, 0, stream>>>(offsets, epk, hbuf, dis, b1, out);

    // ---- layer 2: h2 = relu(out1) @ W2 ; out = A_norm h2 + b2 ----
    gemm_mfma<true><<<gemm_grid, 256, 0, stream>>>(out, wt2hi, wt2lo, hbuf);
    agg_csr<<<(NN * 64) / 256 + 1, 256, 0, stream>>>(offsets, epk, hbuf, dis, b2, out);
}